// Round 6
// baseline (367.970 us; speedup 1.0000x reference)
//
#include <hip/hip_runtime.h>

#define NT 16384
#define DM 4096
#define NE 64
#define TOPK 8
#define NWAVES 8          // waves per workgroup (K-split factor)
#define KCH (DM / NWAVES) // 512 K-elements per wave
#define WIN 16            // k-window per inner step
#define NWIN (KCH / WIN)  // 32 windows
#define NEGINF (-3.402823466e38f)

#define CAT3(a,b,c) a##b##c

// X-macro over the 64 experts: NAMED scalar accumulators (no arrays anywhere).
#define FOR_E(A) A(0) A(1) A(2) A(3) A(4) A(5) A(6) A(7) \
  A(8) A(9) A(10) A(11) A(12) A(13) A(14) A(15) \
  A(16) A(17) A(18) A(19) A(20) A(21) A(22) A(23) \
  A(24) A(25) A(26) A(27) A(28) A(29) A(30) A(31) \
  A(32) A(33) A(34) A(35) A(36) A(37) A(38) A(39) \
  A(40) A(41) A(42) A(43) A(44) A(45) A(46) A(47) \
  A(48) A(49) A(50) A(51) A(52) A(53) A(54) A(55) \
  A(56) A(57) A(58) A(59) A(60) A(61) A(62) A(63)

// 16 groups of 4 experts (LDS reduce + anything float4-grouped)
#define FOR_G(G) G(0,0,1,2,3) G(1,4,5,6,7) G(2,8,9,10,11) G(3,12,13,14,15) \
  G(4,16,17,18,19) G(5,20,21,22,23) G(6,24,25,26,27) G(7,28,29,30,31) \
  G(8,32,33,34,35) G(9,36,37,38,39) G(10,40,41,42,43) G(11,44,45,46,47) \
  G(12,48,49,50,51) G(13,52,53,54,55) G(14,56,57,58,59) G(15,60,61,62,63)

#define DECL(e) float acc##e = 0.f;

// Load a 4-expert W window group (experts eb..eb+3, 16 floats each) into
// named float4 buffer Bf (Bf{j}{v}, j=expert-in-group, v=float4 idx).
#define LOADG(Bf, base, eb) { \
  const float4* _p0 = (const float4*)((base) + (size_t)((eb)+0)*DM); \
  const float4* _p1 = (const float4*)((base) + (size_t)((eb)+1)*DM); \
  const float4* _p2 = (const float4*)((base) + (size_t)((eb)+2)*DM); \
  const float4* _p3 = (const float4*)((base) + (size_t)((eb)+3)*DM); \
  CAT3(Bf,0,0)=_p0[0]; CAT3(Bf,0,1)=_p0[1]; CAT3(Bf,0,2)=_p0[2]; CAT3(Bf,0,3)=_p0[3]; \
  CAT3(Bf,1,0)=_p1[0]; CAT3(Bf,1,1)=_p1[1]; CAT3(Bf,1,2)=_p1[2]; CAT3(Bf,1,3)=_p1[3]; \
  CAT3(Bf,2,0)=_p2[0]; CAT3(Bf,2,1)=_p2[1]; CAT3(Bf,2,2)=_p2[2]; CAT3(Bf,2,3)=_p2[3]; \
  CAT3(Bf,3,0)=_p3[0]; CAT3(Bf,3,1)=_p3[1]; CAT3(Bf,3,2)=_p3[2]; CAT3(Bf,3,3)=_p3[3]; }

// 16-FMA dot of x window (xw0..3) with buffered expert j, into acc##e.
#define FMA1(Bf, j, e) { \
  const float4 _b0 = CAT3(Bf,j,0), _b1 = CAT3(Bf,j,1); \
  const float4 _b2 = CAT3(Bf,j,2), _b3 = CAT3(Bf,j,3); \
  float _s = 0.f; \
  _s = fmaf(xw0.x, _b0.x, _s); _s = fmaf(xw0.y, _b0.y, _s); \
  _s = fmaf(xw0.z, _b0.z, _s); _s = fmaf(xw0.w, _b0.w, _s); \
  _s = fmaf(xw1.x, _b1.x, _s); _s = fmaf(xw1.y, _b1.y, _s); \
  _s = fmaf(xw1.z, _b1.z, _s); _s = fmaf(xw1.w, _b1.w, _s); \
  _s = fmaf(xw2.x, _b2.x, _s); _s = fmaf(xw2.y, _b2.y, _s); \
  _s = fmaf(xw2.z, _b2.z, _s); _s = fmaf(xw2.w, _b2.w, _s); \
  _s = fmaf(xw3.x, _b3.x, _s); _s = fmaf(xw3.y, _b3.y, _s); \
  _s = fmaf(xw3.z, _b3.z, _s); _s = fmaf(xw3.w, _b3.w, _s); \
  acc##e += _s; }

#define FMA4(Bf, e0,e1,e2,e3) \
  FMA1(Bf,0,e0) FMA1(Bf,1,e1) FMA1(Bf,2,e2) FMA1(Bf,3,e3)

#define DUMPG(g,a,b,c,d) \
  *(float4*)&red[_slot][lane][4*(g)] = make_float4(acc##a, acc##b, acc##c, acc##d);
#define DUMP(s) { const int _slot = (s); FOR_G(DUMPG) }

#define ADDG(g,a,b,c,d) { \
  const float4 _t = *(const float4*)&red[_slot][lane][4*(g)]; \
  acc##a += _t.x; acc##b += _t.y; acc##c += _t.z; acc##d += _t.w; }
#define ADDIN(s) { const int _slot = (s); FOR_G(ADDG) }

#define SELE(e) { const bool _b = acc##e > _m; _m = _b ? acc##e : _m; _mi = _b ? (e) : _mi; }
#define CLRE(e) acc##e = (_mi == (e)) ? NEGINF : acc##e;
#define TOPP(p) { float _m = NEGINF; int _mi = 0; FOR_E(SELE) idx##p = _mi; FOR_E(CLRE) }

__global__ __launch_bounds__(512)
__attribute__((amdgpu_waves_per_eu(2, 2)))
void gate_kernel(const float* __restrict__ x,
                 const float* __restrict__ W,
                 int* __restrict__ out) {

  const int lane = threadIdx.x & 63;
  const int wid  = __builtin_amdgcn_readfirstlane((int)(threadIdx.x >> 6));
  const int tok  = blockIdx.x * 64 + lane;
  const int kbase = wid * KCH;

  FOR_E(DECL)

  const float* xrow = x + (size_t)tok * DM + kbase;

  // per-lane x window (16 floats) + next-window prefetch
  float4 xw0, xw1, xw2, xw3, xn0, xn1, xn2, xn3;
  {
    const float4* xp = (const float4*)xrow;
    xw0 = xp[0]; xw1 = xp[1]; xw2 = xp[2]; xw3 = xp[3];
    xn0 = xw0; xn1 = xw1; xn2 = xw2; xn3 = xw3;
  }

  // W register double-buffers: 2 x (4 experts x 4 float4)
  float4 A00,A01,A02,A03, A10,A11,A12,A13, A20,A21,A22,A23, A30,A31,A32,A33;
  float4 B00,B01,B02,B03, B10,B11,B12,B13, B20,B21,B22,B23, B30,B31,B32,B33;

  const float* Wb = W + kbase;
  LOADG(A, Wb, 0)   // prologue: window 0, group 0

  for (int w = 0; w < NWIN; ++w) {
    if (w + 1 < NWIN) {
      const float4* xp = (const float4*)(xrow + (w + 1) * WIN);
      xn0 = xp[0]; xn1 = xp[1]; xn2 = xp[2]; xn3 = xp[3];
    }
    const float* WbN = (w + 1 < NWIN) ? (Wb + WIN) : Wb; // in-bounds tail
    // software pipeline: load group g+1 into the other buffer, FMA group g
    LOADG(B, Wb, 4)    FMA4(A, 0,1,2,3)
    LOADG(A, Wb, 8)    FMA4(B, 4,5,6,7)
    LOADG(B, Wb, 12)   FMA4(A, 8,9,10,11)
    LOADG(A, Wb, 16)   FMA4(B, 12,13,14,15)
    LOADG(B, Wb, 20)   FMA4(A, 16,17,18,19)
    LOADG(A, Wb, 24)   FMA4(B, 20,21,22,23)
    LOADG(B, Wb, 28)   FMA4(A, 24,25,26,27)
    LOADG(A, Wb, 32)   FMA4(B, 28,29,30,31)
    LOADG(B, Wb, 36)   FMA4(A, 32,33,34,35)
    LOADG(A, Wb, 40)   FMA4(B, 36,37,38,39)
    LOADG(B, Wb, 44)   FMA4(A, 40,41,42,43)
    LOADG(A, Wb, 48)   FMA4(B, 44,45,46,47)
    LOADG(B, Wb, 52)   FMA4(A, 48,49,50,51)
    LOADG(A, Wb, 56)   FMA4(B, 52,53,54,55)
    LOADG(B, Wb, 60)   FMA4(A, 56,57,58,59)
    LOADG(A, WbN, 0)   FMA4(B, 60,61,62,63)
    xw0 = xn0; xw1 = xn1; xw2 = xn2; xw3 = xn3;
    Wb += WIN;
  }

  // ---- cross-wave K reduction: pairwise tree via LDS (2 slots) ----
  __shared__ float red[2][64][68]; // 34816 B

  if (wid == 4) DUMP(0)
  if (wid == 5) DUMP(1)
  __syncthreads();
  if (wid == 0) ADDIN(0)
  if (wid == 1) ADDIN(1)
  __syncthreads();
  if (wid == 6) DUMP(0)
  if (wid == 7) DUMP(1)
  __syncthreads();
  if (wid == 2) ADDIN(0)
  if (wid == 3) ADDIN(1)
  __syncthreads();
  if (wid == 2) DUMP(0)
  if (wid == 3) DUMP(1)
  __syncthreads();
  if (wid == 0) ADDIN(0)
  if (wid == 1) ADDIN(1)
  __syncthreads();
  if (wid == 1) DUMP(0)
  __syncthreads();

  if (wid == 0) {
    ADDIN(0)

    // ---- top-8 by repeated argmax (stable: lowest index wins ties) ----
    int idx0, idx1, idx2, idx3, idx4, idx5, idx6, idx7;
    TOPP(0) TOPP(1) TOPP(2) TOPP(3) TOPP(4) TOPP(5) TOPP(6) TOPP(7)

    int4* op = (int4*)(out + (size_t)tok * TOPK);
    op[0] = make_int4(idx0, idx1, idx2, idx3);
    op[1] = make_int4(idx4, idx5, idx6, idx7);
  }
}

extern "C" void kernel_launch(void* const* d_in, const int* in_sizes, int n_in,
                              void* d_out, int out_size, void* d_ws, size_t ws_size,
                              hipStream_t stream) {
  const float* x = (const float*)d_in[0];
  const float* W = (const float*)d_in[1];
  int* out = (int*)d_out;
  (void)in_sizes; (void)n_in; (void)out_size; (void)d_ws; (void)ws_size;

  dim3 grid(NT / 64);   // 256 workgroups, one per 64 tokens
  dim3 block(512);      // 8 waves: K-split
  hipLaunchKernelGGL(gate_kernel, grid, block, 0, stream, x, W, out);
}